// Round 12
// baseline (934.007 us; speedup 1.0000x reference)
//
#include <hip/hip_runtime.h>
#include <hip/hip_cooperative_groups.h>

namespace cg = cooperative_groups;

#define NB 32
#define NC 512
#define NH 56
#define NW 56
#define HW 3136       // 56*56
#define CPB 16        // planes (channels) per chunk in phase 1
#define NPART 32      // NC/CPB partial chunks
#define GRID 1024     // cooperative grid: 4 blocks/CU * 256 CU

// ================= phase bodies (round-7 verified code, verbatim) =================

// ---- Phase 1: per-(b,c) mask + channel max/sum partials (k12 of round 7) ----
__device__ __forceinline__ void ph1_maskpart(const float* __restrict__ x,
                                             float* mask, float* pmax, double* psum,
                                             int bid, int tid) {
    const int b = bid >> 5;
    const int ch = bid & 31;
    const int c0 = ch * CPB;
    __shared__ double rsum[4];
    __shared__ float rmax[4];
    const bool has4 = (tid < 16);   // 784 float4s = 3*256 + 16
    float am[16];
    double as[16];
#pragma unroll
    for (int k = 0; k < 16; k++) { am[k] = 0.f; as[k] = 0.0; }

    for (int p = 0; p < CPB; p++) {
        const float4* px = (const float4*)(x + (size_t)(b * NC + c0 + p) * HW);
        float v[16];
#pragma unroll
        for (int k = 0; k < 4; k++) {
            if (k < 3 || has4) {
                float4 t = px[tid + k * 256];
                v[4 * k + 0] = fmaxf(t.x, 0.f);
                v[4 * k + 1] = fmaxf(t.y, 0.f);
                v[4 * k + 2] = fmaxf(t.z, 0.f);
                v[4 * k + 3] = fmaxf(t.w, 0.f);
            } else {
                v[4 * k + 0] = 0.f; v[4 * k + 1] = 0.f;
                v[4 * k + 2] = 0.f; v[4 * k + 3] = 0.f;
            }
        }
        float lmax = 0.f;
        double lsum = 0.0;
#pragma unroll
        for (int k = 0; k < 16; k++) {
            lmax = fmaxf(lmax, v[k]);
            lsum += (double)v[k];
        }
        for (int off = 32; off; off >>= 1) {
            lsum += __shfl_xor(lsum, off);
            lmax = fmaxf(lmax, __shfl_xor(lmax, off));
        }
        __syncthreads();
        if ((tid & 63) == 0) { rsum[tid >> 6] = lsum; rmax[tid >> 6] = lmax; }
        __syncthreads();
        double s = rsum[0] + rsum[1] + rsum[2] + rsum[3];
        float m = fmaxf(fmaxf(rmax[0], rmax[1]), fmaxf(rmax[2], rmax[3]));
        float avg = (float)(s / 3136.0);
        float mk = ((m - avg) < 0.5f) ? 0.f : 1.f;
        if (tid == 0) mask[b * NC + c0 + p] = mk;
        if (mk != 0.f) {
#pragma unroll
            for (int k = 0; k < 16; k++) {
                am[k] = fmaxf(am[k], v[k]);
                as[k] += (double)v[k];
            }
        }
    }
    const size_t pb = ((size_t)ch * NB + b) * HW;
#pragma unroll
    for (int k = 0; k < 4; k++) {
        if (k < 3 || has4) {
            const int pos = 4 * (tid + k * 256);
            *(float4*)(pmax + pb + pos) =
                make_float4(am[4 * k], am[4 * k + 1], am[4 * k + 2], am[4 * k + 3]);
            *(double2*)(psum + pb + pos)     = make_double2(as[4 * k],     as[4 * k + 1]);
            *(double2*)(psum + pb + pos + 2) = make_double2(as[4 * k + 2], as[4 * k + 3]);
        }
    }
}

// ---- Phase 2: reduce chunk partials (deterministic ascending order) -> bb ----
__device__ __forceinline__ void ph2_bbfin(const float* pmax, const double* psum,
                                          float* bb, int i) {
    const int b = i / HW, pos = i % HW;
    float m = 0.f;
    double s = 0.0;
#pragma unroll 4
    for (int ch = 0; ch < NPART; ch++) {
        const size_t idx = ((size_t)ch * NB + b) * HW + pos;
        m = fmaxf(m, pmax[idx]);
        s += psum[idx];
    }
    double cmean = s * (1.0 / 512.0);
    double d = fabs((double)m - cmean);
    bb[i] = (float)(1.0 - exp(-d));
}

// ---- Phase 3: per-plane x_max and pooled of x2 = bb*x1 (k2b of round 7) ----
__device__ __forceinline__ void ph3_stats(const float* __restrict__ x,
                                          const float* mask, const float* bb,
                                          float* xmax, float* pooled,
                                          int plane, int tid) {
    const int b = plane >> 9;
    const float4* px = (const float4*)(x + (size_t)plane * HW);
    const float4* pbb = (const float4*)(bb + (size_t)b * HW);
    const float mk = mask[plane];
    float m = 0.f;
    double s = 0.0;
    for (int i = tid; i < HW / 4; i += 256) {
        float4 v = px[i];
        float4 bv = pbb[i];
        float x0 = fmaxf(v.x, 0.f) * mk * bv.x;  // identical fp32 chain as phase 5
        float x1 = fmaxf(v.y, 0.f) * mk * bv.y;
        float x2 = fmaxf(v.z, 0.f) * mk * bv.z;
        float x3 = fmaxf(v.w, 0.f) * mk * bv.w;
        m = fmaxf(m, fmaxf(fmaxf(x0, x1), fmaxf(x2, x3)));
        s += (double)x0 + (double)x1 + (double)x2 + (double)x3;
    }
    for (int off = 32; off; off >>= 1) {
        s += __shfl_xor(s, off);
        m = fmaxf(m, __shfl_xor(m, off));
    }
    __shared__ double ssum[4];
    __shared__ float smax[4];
    int wid = tid >> 6, lane = tid & 63;
    if (lane == 0) { ssum[wid] = s; smax[wid] = m; }
    __syncthreads();
    if (tid == 0) {
        double st = ssum[0] + ssum[1] + ssum[2] + ssum[3];
        float mt = fmaxf(fmaxf(smax[0], smax[1]), fmaxf(smax[2], smax[3]));
        xmax[plane] = mt;
        pooled[plane] = (float)(st / 3136.0);
    }
    __syncthreads();   // protect ssum/smax reuse by the next plane iteration
}

// ---- Phase 4: FC gates (wave-per-output dot products) -> thres ----
__device__ __forceinline__ void ph4_gates(const float* pooled,
                                          const float* __restrict__ W1,
                                          const float* __restrict__ W3,
                                          const float* xmax, float* thres,
                                          int bid, int tid) {
    int wave = tid >> 6, lane = tid & 63;
    int task0 = (bid * 4 + wave) * 4;
    for (int t = 0; t < 4; t++) {
        int task = task0 + t;                       // b*512 + j
        int b = task >> 9, j = task & 511;
        const float* r1 = W1 + j * 512;
        const float* r3 = W3 + j * 512;
        const float* pr = pooled + b * 512;
        double s1 = 0.0, s3 = 0.0;
        for (int k = lane; k < 512; k += 64) {
            double p = (double)pr[k];
            s1 += p * (double)r1[k];
            s3 += p * (double)r3[k];
        }
        for (int off = 32; off; off >>= 1) {
            s1 += __shfl_xor(s1, off);
            s3 += __shfl_xor(s3, off);
        }
        if (lane == 0) {
            float c1 = (float)(1.0 / (1.0 + exp(-s1)));   // sigmoid
            double r = s3 > 0.0 ? s3 : 0.0;               // relu
            float c3 = (float)((r < 1.0) ? 1.2 : r);
            thres[task] = c1 * c3 * xmax[task];           // np's fp32 mul order
        }
    }
}

// ---- Phase 5: recompute x2, threshold, write fp32 out (no barriers) ----
__device__ __forceinline__ void ph5_out(const float* __restrict__ x,
                                        const float* mask, const float* bb,
                                        const float* thres, float* out,
                                        int plane, int tid) {
    const int b = plane >> 9;
    const float4* px = (const float4*)(x + (size_t)plane * HW);
    float4* po = (float4*)(out + (size_t)plane * HW);
    const float4* pbb = (const float4*)(bb + (size_t)b * HW);
    const float th = thres[plane];
    const float mk = mask[plane];
    for (int i = tid; i < HW / 4; i += 256) {
        float4 v = px[i];
        float4 bv = pbb[i];
        float x0 = fmaxf(v.x, 0.f) * mk * bv.x;  // identical fp32 chain as phase 3
        float x1 = fmaxf(v.y, 0.f) * mk * bv.y;
        float x2 = fmaxf(v.z, 0.f) * mk * bv.z;
        float x3 = fmaxf(v.w, 0.f) * mk * bv.w;
        float4 o;
        o.x = (x0 < th) ? 0.f : x0;
        o.y = (x1 < th) ? 0.f : x1;
        o.z = (x2 < th) ? 0.f : x2;
        o.w = (x3 < th) ? 0.f : x3;
        po[i] = o;
    }
}

// ================= single cooperative kernel (5 phases, 4 grid syncs) =================
__global__ __launch_bounds__(256, 4) void k_all(const float* __restrict__ x,
                                                const float* __restrict__ W1,
                                                const float* __restrict__ W3,
                                                float* out, float* mask, float* bb,
                                                float* xmax, float* pooled, float* thres,
                                                float* pmax, double* psum) {
    cg::grid_group g = cg::this_grid();
    const int bid = blockIdx.x, tid = threadIdx.x;

    ph1_maskpart(x, mask, pmax, psum, bid, tid);
    g.sync();
    if (bid < NB * HW / 256) ph2_bbfin(pmax, psum, bb, bid * 256 + tid);
    g.sync();
    for (int pl = bid; pl < NB * NC; pl += GRID) ph3_stats(x, mask, bb, xmax, pooled, pl, tid);
    g.sync();
    ph4_gates(pooled, W1, W3, xmax, thres, bid, tid);
    g.sync();
    for (int pl = bid; pl < NB * NC; pl += GRID) ph5_out(x, mask, bb, thres, out, pl, tid);
}

// ================= fallback: round-7 5-kernel sequence (same phase bodies) =================
__global__ __launch_bounds__(256) void k12_s(const float* __restrict__ x, float* mask,
                                             float* pmax, double* psum) {
    ph1_maskpart(x, mask, pmax, psum, blockIdx.x, threadIdx.x);
}
__global__ __launch_bounds__(256) void k2bb_s(const float* pmax, const double* psum, float* bb) {
    ph2_bbfin(pmax, psum, bb, blockIdx.x * 256 + threadIdx.x);
}
__global__ __launch_bounds__(256) void k2b_s(const float* __restrict__ x, const float* mask,
                                             const float* bb, float* xmax, float* pooled) {
    ph3_stats(x, mask, bb, xmax, pooled, blockIdx.x, threadIdx.x);
}
__global__ __launch_bounds__(256) void k3_s(const float* pooled, const float* __restrict__ W1,
                                            const float* __restrict__ W3, const float* xmax,
                                            float* thres) {
    ph4_gates(pooled, W1, W3, xmax, thres, blockIdx.x, threadIdx.x);
}
__global__ __launch_bounds__(256) void k4_s(const float* __restrict__ x, const float* mask,
                                            const float* bb, const float* thres, float* out) {
    ph5_out(x, mask, bb, thres, out, blockIdx.x, threadIdx.x);
}

extern "C" void kernel_launch(void* const* d_in, const int* in_sizes, int n_in,
                              void* d_out, int out_size, void* d_ws, size_t ws_size,
                              hipStream_t stream) {
    const float* x  = (const float*)d_in[0];
    const float* W1 = (const float*)d_in[1];
    const float* W3 = (const float*)d_in[2];
    float* out = (float*)d_out;
    float* ws = (float*)d_ws;
    // ws layout (float slots) — same verified 648 KB footprint:
    float* bb     = ws;            // [0, 100352)
    float* mask   = ws + 100352;   // [100352, 116736)
    float* xmax   = ws + 116736;   // [116736, 133120)
    float* pooled = ws + 133120;   // [133120, 149504)
    float* thres  = ws + 149504;   // [149504, 165888)
    // chunk partials in d_out scratch (38.5 MB of 205 MB), consumed in phase 2
    // strictly before phase 5 overwrites d_out with the real output:
    double* psum = (double*)d_out;                               // 25,690,112 B
    float* pmax  = (float*)d_out + (size_t)NPART * NB * HW * 2;  // 12,845,056 B after

    void* args[] = {(void*)&x, (void*)&W1, (void*)&W3, (void*)&out, (void*)&mask,
                    (void*)&bb, (void*)&xmax, (void*)&pooled, (void*)&thres,
                    (void*)&pmax, (void*)&psum};
    hipError_t e = hipLaunchCooperativeKernel((const void*)k_all, dim3(GRID), dim3(256),
                                              args, 0, stream);
    if (e != hipSuccess) {
        (void)hipGetLastError();  // clear; fall back to the round-7 sequence
        hipLaunchKernelGGL(k12_s,  dim3(NB * NPART),    dim3(256), 0, stream, x, mask, pmax, psum);
        hipLaunchKernelGGL(k2bb_s, dim3(NB * HW / 256), dim3(256), 0, stream, pmax, psum, bb);
        hipLaunchKernelGGL(k2b_s,  dim3(NB * NC),       dim3(256), 0, stream, x, mask, bb, xmax, pooled);
        hipLaunchKernelGGL(k3_s,   dim3(1024),          dim3(256), 0, stream, pooled, W1, W3, xmax, thres);
        hipLaunchKernelGGL(k4_s,   dim3(NB * NC),       dim3(256), 0, stream, x, mask, bb, thres, out);
    }
}

// Round 14
// 459.871 us; speedup vs baseline: 2.0310x; 2.0310x over previous
//
#include <hip/hip_runtime.h>

#define NB 32
#define NC 512
#define NH 56
#define NW 56
#define HW 3136       // 56*56
#define CHW 1605632   // 512*3136
#define CPB 32        // planes (channels) per chunk in k2p
#define NPART 16      // NC/CPB partial chunks
#define HSPLIT 4      // hw quarters per chunk in k2p
#define QF4 196       // float4s per hw quarter (784/4)

// ---------------- K1: per-(b,c) mean/max of relu(x) -> mask ----------------
// Verbatim the original harness-verified K1.
__global__ __launch_bounds__(256) void k1_mask(const float* __restrict__ x,
                                               float* __restrict__ mask) {
    const int plane = blockIdx.x;  // b*512 + c
    const float4* px = (const float4*)(x + (size_t)plane * HW);
    float lmax = 0.f;
    double lsum = 0.0;
    for (int i = threadIdx.x; i < HW / 4; i += 256) {
        float4 v = px[i];
        float f0 = fmaxf(v.x, 0.f), f1 = fmaxf(v.y, 0.f);
        float f2 = fmaxf(v.z, 0.f), f3 = fmaxf(v.w, 0.f);
        lmax = fmaxf(lmax, fmaxf(fmaxf(f0, f1), fmaxf(f2, f3)));
        lsum += (double)f0 + (double)f1 + (double)f2 + (double)f3;
    }
    for (int off = 32; off; off >>= 1) {
        lsum += __shfl_xor(lsum, off);
        lmax = fmaxf(lmax, __shfl_xor(lmax, off));
    }
    __shared__ double ssum[4];
    __shared__ float smax[4];
    int wid = threadIdx.x >> 6, lane = threadIdx.x & 63;
    if (lane == 0) { ssum[wid] = lsum; smax[wid] = lmax; }
    __syncthreads();
    if (threadIdx.x == 0) {
        double s = ssum[0] + ssum[1] + ssum[2] + ssum[3];
        float m = fmaxf(fmaxf(smax[0], smax[1]), fmaxf(smax[2], smax[3]));
        float avg = (float)(s / 3136.0);
        mask[plane] = ((m - avg) < 0.5f) ? 0.f : 1.f;
    }
}

// ---- K2p: barrier-free channel max/sum partials, hw-split for occupancy ----
// grid = NB * NPART * HSPLIT = 2048 blocks (8/CU). Block (b, ch, h) streams
// CPB=32 contiguous planes over hw-quarter h: thread t<196 owns float4
// (h*196 + t) of every plane — one independent load per plane, zero barriers,
// zero shuffles. Accumulate v*mk (mk in {0,1}) is exact; channel order is
// ascending within chunk, chunks ascending in k2bb — bit-identical to the
// round-7/8 passed runs.
__global__ __launch_bounds__(256) void k2p_part(const float* __restrict__ x,
                                                const float* __restrict__ mask,
                                                float* __restrict__ pmax,
                                                double* __restrict__ psum) {
    const int b = blockIdx.x >> 6;
    const int ch = (blockIdx.x >> 2) & 15;
    const int h = blockIdx.x & 3;
    const int c0 = ch * CPB;
    const int tid = threadIdx.x;
    if (tid >= QF4) return;                 // 196 active threads, BW-bound anyway
    const int i4 = h * QF4 + tid;           // this thread's float4 index in plane
    float am[4];
    double as[4];
#pragma unroll
    for (int k = 0; k < 4; k++) { am[k] = 0.f; as[k] = 0.0; }

#pragma unroll 4
    for (int p = 0; p < CPB; p++) {
        const int c = c0 + p;
        const float mk = mask[b * NC + c];  // 0.0 or 1.0
        float4 t = *(const float4*)(x + (size_t)(b * NC + c) * HW + 4 * i4);
        float f0 = fmaxf(t.x, 0.f) * mk;
        float f1 = fmaxf(t.y, 0.f) * mk;
        float f2 = fmaxf(t.z, 0.f) * mk;
        float f3 = fmaxf(t.w, 0.f) * mk;
        am[0] = fmaxf(am[0], f0);
        am[1] = fmaxf(am[1], f1);
        am[2] = fmaxf(am[2], f2);
        am[3] = fmaxf(am[3], f3);
        as[0] += (double)f0;
        as[1] += (double)f1;
        as[2] += (double)f2;
        as[3] += (double)f3;
    }
    // coalesced private-partial writeout (no atomics)
    const size_t pb = ((size_t)ch * NB + b) * HW;
    const int pos = 4 * i4;
    *(float4*)(pmax + pb + pos) = make_float4(am[0], am[1], am[2], am[3]);
    *(double2*)(psum + pb + pos)     = make_double2(as[0], as[1]);
    *(double2*)(psum + pb + pos + 2) = make_double2(as[2], as[3]);
}

// ---- K2bb: reduce chunk partials (deterministic order) -> bb in ws ----
__global__ __launch_bounds__(256) void k2bb_fin(const float* __restrict__ pmax,
                                                const double* __restrict__ psum,
                                                float* __restrict__ bb) {
    const int i = blockIdx.x * 256 + threadIdx.x;  // grid*block == NB*HW exactly
    const int b = i / HW, pos = i % HW;
    float m = 0.f;
    double s = 0.0;
#pragma unroll 4
    for (int ch = 0; ch < NPART; ch++) {
        const size_t idx = ((size_t)ch * NB + b) * HW + pos;
        m = fmaxf(m, pmax[idx]);
        s += psum[idx];
    }
    double cmean = s * (1.0 / 512.0);
    double d = fabs((double)m - cmean);
    bb[i] = (float)(1.0 - exp(-d));
}

// ---- K2b: per-(b,c) plane: x_max and pooled of x2 = bb*x1 (one block) ----
__global__ __launch_bounds__(256) void k2b_stats(const float* __restrict__ x,
                                                 const float* __restrict__ mask,
                                                 const float* __restrict__ bb,
                                                 float* __restrict__ xmax,
                                                 float* __restrict__ pooled) {
    const int plane = blockIdx.x;  // b*512 + c
    const int b = plane >> 9;
    const float4* px = (const float4*)(x + (size_t)plane * HW);
    const float4* pbb = (const float4*)(bb + (size_t)b * HW);
    const float mk = mask[plane];
    float m = 0.f;
    double s = 0.0;
    for (int i = threadIdx.x; i < HW / 4; i += 256) {
        float4 v = px[i];
        float4 bv = pbb[i];
        float x0 = fmaxf(v.x, 0.f) * mk * bv.x;  // identical fp32 chain as K4
        float x1 = fmaxf(v.y, 0.f) * mk * bv.y;
        float x2 = fmaxf(v.z, 0.f) * mk * bv.z;
        float x3 = fmaxf(v.w, 0.f) * mk * bv.w;
        m = fmaxf(m, fmaxf(fmaxf(x0, x1), fmaxf(x2, x3)));
        s += (double)x0 + (double)x1 + (double)x2 + (double)x3;
    }
    for (int off = 32; off; off >>= 1) {
        s += __shfl_xor(s, off);
        m = fmaxf(m, __shfl_xor(m, off));
    }
    __shared__ double ssum[4];
    __shared__ float smax[4];
    int wid = threadIdx.x >> 6, lane = threadIdx.x & 63;
    if (lane == 0) { ssum[wid] = s; smax[wid] = m; }
    __syncthreads();
    if (threadIdx.x == 0) {
        double st = ssum[0] + ssum[1] + ssum[2] + ssum[3];
        float mt = fmaxf(fmaxf(smax[0], smax[1]), fmaxf(smax[2], smax[3]));
        xmax[plane] = mt;
        pooled[plane] = (float)(st / 3136.0);
    }
}

// ------------- K3: FC gates (wave-per-output dot products) -> thres -------------
__global__ __launch_bounds__(256) void k3_gates(const float* __restrict__ pooled,
                                                const float* __restrict__ W1,
                                                const float* __restrict__ W3,
                                                const float* __restrict__ xmax,
                                                float* __restrict__ thres) {
    int wave = threadIdx.x >> 6, lane = threadIdx.x & 63;
    int task0 = (blockIdx.x * 4 + wave) * 4;
    for (int t = 0; t < 4; t++) {
        int task = task0 + t;                       // b*512 + j
        int b = task >> 9, j = task & 511;
        const float* r1 = W1 + j * 512;
        const float* r3 = W3 + j * 512;
        const float* pr = pooled + b * 512;
        double s1 = 0.0, s3 = 0.0;
        for (int k = lane; k < 512; k += 64) {
            double p = (double)pr[k];
            s1 += p * (double)r1[k];
            s3 += p * (double)r3[k];
        }
        for (int off = 32; off; off >>= 1) {
            s1 += __shfl_xor(s1, off);
            s3 += __shfl_xor(s3, off);
        }
        if (lane == 0) {
            float c1 = (float)(1.0 / (1.0 + exp(-s1)));   // sigmoid
            double r = s3 > 0.0 ? s3 : 0.0;               // relu
            float c3 = (float)((r < 1.0) ? 1.2 : r);
            thres[task] = c1 * c3 * xmax[task];           // np's fp32 mul order
        }
    }
}

// ---------------- K4: recompute x2, threshold, write fp32 out ----------------
__global__ __launch_bounds__(256) void k4_out(const float* __restrict__ x,
                                              const float* __restrict__ mask,
                                              const float* __restrict__ bb,
                                              const float* __restrict__ thres,
                                              float* __restrict__ out) {
    const int plane = blockIdx.x;
    const int b = plane >> 9;
    const float4* px = (const float4*)(x + (size_t)plane * HW);
    float4* po = (float4*)(out + (size_t)plane * HW);
    const float4* pbb = (const float4*)(bb + (size_t)b * HW);
    const float th = thres[plane];
    const float mk = mask[plane];
    for (int i = threadIdx.x; i < HW / 4; i += 256) {
        float4 v = px[i];
        float4 bv = pbb[i];
        float x0 = fmaxf(v.x, 0.f) * mk * bv.x;  // identical fp32 chain as K2b
        float x1 = fmaxf(v.y, 0.f) * mk * bv.y;
        float x2 = fmaxf(v.z, 0.f) * mk * bv.z;
        float x3 = fmaxf(v.w, 0.f) * mk * bv.w;
        float4 o;
        o.x = (x0 < th) ? 0.f : x0;
        o.y = (x1 < th) ? 0.f : x1;
        o.z = (x2 < th) ? 0.f : x2;
        o.w = (x3 < th) ? 0.f : x3;
        po[i] = o;
    }
}

extern "C" void kernel_launch(void* const* d_in, const int* in_sizes, int n_in,
                              void* d_out, int out_size, void* d_ws, size_t ws_size,
                              hipStream_t stream) {
    const float* x  = (const float*)d_in[0];
    const float* W1 = (const float*)d_in[1];
    const float* W3 = (const float*)d_in[2];
    float* out = (float*)d_out;
    float* ws = (float*)d_ws;
    // ws layout (float slots) — same verified 648 KB footprint:
    //   bb     : [0, 100352)
    //   mask   : [100352, 116736)
    //   xmax   : [116736, 133120)
    //   pooled : [133120, 149504)
    //   thres  : [149504, 165888)   total 663,552 B
    float* bb     = ws;
    float* mask   = ws + 100352;
    float* xmax   = ws + 116736;
    float* pooled = ws + 133120;
    float* thres  = ws + 149504;
    // chunk partials in d_out scratch (19.3 MB of 205 MB), consumed by k2bb
    // strictly before k4 overwrites d_out with the real output:
    //   psum : NPART*NB*HW doubles at offset 0        (12,845,056 B)
    //   pmax : NPART*NB*HW floats  after psum         ( 6,422,528 B)
    double* psum = (double*)d_out;
    float* pmax  = (float*)d_out + (size_t)NPART * NB * HW * 2;  // *2: f64->f32 slots

    hipLaunchKernelGGL(k1_mask,  dim3(NB * NC),                dim3(256), 0, stream, x, mask);
    hipLaunchKernelGGL(k2p_part, dim3(NB * NPART * HSPLIT),    dim3(256), 0, stream,
                       x, mask, pmax, psum);
    hipLaunchKernelGGL(k2bb_fin, dim3(NB * HW / 256),          dim3(256), 0, stream,
                       pmax, psum, bb);
    hipLaunchKernelGGL(k2b_stats, dim3(NB * NC), dim3(256), 0, stream,
                       x, mask, bb, xmax, pooled);
    hipLaunchKernelGGL(k3_gates,  dim3(1024),    dim3(256), 0, stream,
                       pooled, W1, W3, xmax, thres);
    hipLaunchKernelGGL(k4_out,    dim3(NB * NC), dim3(256), 0, stream,
                       x, mask, bb, thres, out);
}

// Round 15
// 450.441 us; speedup vs baseline: 2.0735x; 1.0209x over previous
//
#include <hip/hip_runtime.h>

#define NB 32
#define NC 512
#define NH 56
#define NW 56
#define HW 3136       // 56*56
#define CHW 1605632   // 512*3136
#define CPB 16        // planes (channels) per block in k12
#define NPART 32      // NC/CPB partial chunks

// ---- K12: fused mask + channel max/sum partials (round-7 449µs kernel with
// double-buffered LDS reduce slots -> ONE barrier per plane instead of two) ----
// grid = NB * NPART = 1024 blocks; block (b, chunk) streams CPB contiguous
// planes. Register-resident accumulators: thread t owns spatial positions
// {4i..4i+3 : i in {t, t+256, t+512} U ({t+768} if t<16)}. No atomics:
// private partials written coalesced to d_out scratch; k2bb reduces
// deterministically (ascending chunk), bit-identical order to round 7.
__global__ __launch_bounds__(256) void k12_maskbb(const float* __restrict__ x,
                                                  float* __restrict__ mask,
                                                  float* __restrict__ pmax,
                                                  double* __restrict__ psum) {
    const int b = blockIdx.x >> 5;
    const int ch = blockIdx.x & 31;
    const int c0 = ch * CPB;
    const int tid = threadIdx.x;
    __shared__ double rsum[2][4];   // [p&1][wave] — double-buffered
    __shared__ float rmax[2][4];
    const bool has4 = (tid < 16);   // 784 float4s = 3*256 + 16
    float am[16];
    double as[16];
#pragma unroll
    for (int k = 0; k < 16; k++) { am[k] = 0.f; as[k] = 0.0; }

    for (int p = 0; p < CPB; p++) {
        const float4* px = (const float4*)(x + (size_t)(b * NC + c0 + p) * HW);
        float v[16];
#pragma unroll
        for (int k = 0; k < 4; k++) {
            if (k < 3 || has4) {
                float4 t = px[tid + k * 256];
                v[4 * k + 0] = fmaxf(t.x, 0.f);
                v[4 * k + 1] = fmaxf(t.y, 0.f);
                v[4 * k + 2] = fmaxf(t.z, 0.f);
                v[4 * k + 3] = fmaxf(t.w, 0.f);
            } else {
                v[4 * k + 0] = 0.f; v[4 * k + 1] = 0.f;
                v[4 * k + 2] = 0.f; v[4 * k + 3] = 0.f;
            }
        }
        // per-thread reduce in the same order as the verified chain
        float lmax = 0.f;
        double lsum = 0.0;
#pragma unroll
        for (int k = 0; k < 16; k++) {
            lmax = fmaxf(lmax, v[k]);
            lsum += (double)v[k];
        }
        for (int off = 32; off; off >>= 1) {
            lsum += __shfl_xor(lsum, off);
            lmax = fmaxf(lmax, __shfl_xor(lmax, off));
        }
        const int slot = p & 1;
        if ((tid & 63) == 0) { rsum[slot][tid >> 6] = lsum; rmax[slot][tid >> 6] = lmax; }
        __syncthreads();
        // safe: iteration p+1 writes slot^1; next write to THIS slot is at p+2,
        // which no thread reaches before all threads pass the p+1 barrier.
        double s = rsum[slot][0] + rsum[slot][1] + rsum[slot][2] + rsum[slot][3];
        float m = fmaxf(fmaxf(rmax[slot][0], rmax[slot][1]),
                        fmaxf(rmax[slot][2], rmax[slot][3]));
        float avg = (float)(s / 3136.0);
        float mk = ((m - avg) < 0.5f) ? 0.f : 1.f;
        if (tid == 0) mask[b * NC + c0 + p] = mk;
        if (mk != 0.f) {
#pragma unroll
            for (int k = 0; k < 16; k++) {
                am[k] = fmaxf(am[k], v[k]);
                as[k] += (double)v[k];
            }
        }
    }
    // coalesced private-partial writeout (no atomics)
    const size_t pb = ((size_t)ch * NB + b) * HW;
#pragma unroll
    for (int k = 0; k < 4; k++) {
        if (k < 3 || has4) {
            const int pos = 4 * (tid + k * 256);
            *(float4*)(pmax + pb + pos) =
                make_float4(am[4 * k], am[4 * k + 1], am[4 * k + 2], am[4 * k + 3]);
            *(double2*)(psum + pb + pos)     = make_double2(as[4 * k],     as[4 * k + 1]);
            *(double2*)(psum + pb + pos + 2) = make_double2(as[4 * k + 2], as[4 * k + 3]);
        }
    }
}

// ---- K2bb: reduce chunk partials (deterministic order) -> bb in ws ----
__global__ __launch_bounds__(256) void k2bb_fin(const float* __restrict__ pmax,
                                                const double* __restrict__ psum,
                                                float* __restrict__ bb) {
    const int i = blockIdx.x * 256 + threadIdx.x;  // grid*block == NB*HW exactly
    const int b = i / HW, pos = i % HW;
    float m = 0.f;
    double s = 0.0;
#pragma unroll 4
    for (int ch = 0; ch < NPART; ch++) {
        const size_t idx = ((size_t)ch * NB + b) * HW + pos;
        m = fmaxf(m, pmax[idx]);
        s += psum[idx];
    }
    double cmean = s * (1.0 / 512.0);
    double d = fabs((double)m - cmean);
    bb[i] = (float)(1.0 - exp(-d));
}

// ---- K2b: per-(b,c) plane: x_max and pooled of x2 = bb*x1 (one block) ----
__global__ __launch_bounds__(256) void k2b_stats(const float* __restrict__ x,
                                                 const float* __restrict__ mask,
                                                 const float* __restrict__ bb,
                                                 float* __restrict__ xmax,
                                                 float* __restrict__ pooled) {
    const int plane = blockIdx.x;  // b*512 + c
    const int b = plane >> 9;
    const float4* px = (const float4*)(x + (size_t)plane * HW);
    const float4* pbb = (const float4*)(bb + (size_t)b * HW);
    const float mk = mask[plane];
    float m = 0.f;
    double s = 0.0;
    for (int i = threadIdx.x; i < HW / 4; i += 256) {
        float4 v = px[i];
        float4 bv = pbb[i];
        float x0 = fmaxf(v.x, 0.f) * mk * bv.x;  // identical fp32 chain as K4
        float x1 = fmaxf(v.y, 0.f) * mk * bv.y;
        float x2 = fmaxf(v.z, 0.f) * mk * bv.z;
        float x3 = fmaxf(v.w, 0.f) * mk * bv.w;
        m = fmaxf(m, fmaxf(fmaxf(x0, x1), fmaxf(x2, x3)));
        s += (double)x0 + (double)x1 + (double)x2 + (double)x3;
    }
    for (int off = 32; off; off >>= 1) {
        s += __shfl_xor(s, off);
        m = fmaxf(m, __shfl_xor(m, off));
    }
    __shared__ double ssum[4];
    __shared__ float smax[4];
    int wid = threadIdx.x >> 6, lane = threadIdx.x & 63;
    if (lane == 0) { ssum[wid] = s; smax[wid] = m; }
    __syncthreads();
    if (threadIdx.x == 0) {
        double st = ssum[0] + ssum[1] + ssum[2] + ssum[3];
        float mt = fmaxf(fmaxf(smax[0], smax[1]), fmaxf(smax[2], smax[3]));
        xmax[plane] = mt;
        pooled[plane] = (float)(st / 3136.0);
    }
}

// ------------- K3: FC gates (wave-per-output dot products) -> thres -------------
__global__ __launch_bounds__(256) void k3_gates(const float* __restrict__ pooled,
                                                const float* __restrict__ W1,
                                                const float* __restrict__ W3,
                                                const float* __restrict__ xmax,
                                                float* __restrict__ thres) {
    int wave = threadIdx.x >> 6, lane = threadIdx.x & 63;
    int task0 = (blockIdx.x * 4 + wave) * 4;
    for (int t = 0; t < 4; t++) {
        int task = task0 + t;                       // b*512 + j
        int b = task >> 9, j = task & 511;
        const float* r1 = W1 + j * 512;
        const float* r3 = W3 + j * 512;
        const float* pr = pooled + b * 512;
        double s1 = 0.0, s3 = 0.0;
        for (int k = lane; k < 512; k += 64) {
            double p = (double)pr[k];
            s1 += p * (double)r1[k];
            s3 += p * (double)r3[k];
        }
        for (int off = 32; off; off >>= 1) {
            s1 += __shfl_xor(s1, off);
            s3 += __shfl_xor(s3, off);
        }
        if (lane == 0) {
            float c1 = (float)(1.0 / (1.0 + exp(-s1)));   // sigmoid
            double r = s3 > 0.0 ? s3 : 0.0;               // relu
            float c3 = (float)((r < 1.0) ? 1.2 : r);
            thres[task] = c1 * c3 * xmax[task];           // np's fp32 mul order
        }
    }
}

// ---------------- K4: recompute x2, threshold, write fp32 out ----------------
__global__ __launch_bounds__(256) void k4_out(const float* __restrict__ x,
                                              const float* __restrict__ mask,
                                              const float* __restrict__ bb,
                                              const float* __restrict__ thres,
                                              float* __restrict__ out) {
    const int plane = blockIdx.x;
    const int b = plane >> 9;
    const float4* px = (const float4*)(x + (size_t)plane * HW);
    float4* po = (float4*)(out + (size_t)plane * HW);
    const float4* pbb = (const float4*)(bb + (size_t)b * HW);
    const float th = thres[plane];
    const float mk = mask[plane];
    for (int i = threadIdx.x; i < HW / 4; i += 256) {
        float4 v = px[i];
        float4 bv = pbb[i];
        float x0 = fmaxf(v.x, 0.f) * mk * bv.x;  // identical fp32 chain as K2b
        float x1 = fmaxf(v.y, 0.f) * mk * bv.y;
        float x2 = fmaxf(v.z, 0.f) * mk * bv.z;
        float x3 = fmaxf(v.w, 0.f) * mk * bv.w;
        float4 o;
        o.x = (x0 < th) ? 0.f : x0;
        o.y = (x1 < th) ? 0.f : x1;
        o.z = (x2 < th) ? 0.f : x2;
        o.w = (x3 < th) ? 0.f : x3;
        po[i] = o;
    }
}

extern "C" void kernel_launch(void* const* d_in, const int* in_sizes, int n_in,
                              void* d_out, int out_size, void* d_ws, size_t ws_size,
                              hipStream_t stream) {
    const float* x  = (const float*)d_in[0];
    const float* W1 = (const float*)d_in[1];
    const float* W3 = (const float*)d_in[2];
    float* out = (float*)d_out;
    float* ws = (float*)d_ws;
    // ws layout (float slots) — same verified 648 KB footprint:
    //   bb     : [0, 100352)
    //   mask   : [100352, 116736)
    //   xmax   : [116736, 133120)
    //   pooled : [133120, 149504)
    //   thres  : [149504, 165888)   total 663,552 B
    float* bb     = ws;
    float* mask   = ws + 100352;
    float* xmax   = ws + 116736;
    float* pooled = ws + 133120;
    float* thres  = ws + 149504;
    // chunk partials live in d_out scratch (38.5 MB of 205 MB), consumed by
    // k2bb strictly before k4 overwrites d_out with the real output:
    //   psum : NPART*NB*HW doubles at offset 0        (25,690,112 B)
    //   pmax : NPART*NB*HW floats  after psum         (12,845,056 B)
    double* psum = (double*)d_out;
    float* pmax  = (float*)d_out + (size_t)NPART * NB * HW * 2;  // *2: f64->f32 slots

    hipLaunchKernelGGL(k12_maskbb, dim3(NB * NPART),    dim3(256), 0, stream,
                       x, mask, pmax, psum);
    hipLaunchKernelGGL(k2bb_fin,   dim3(NB * HW / 256), dim3(256), 0, stream,
                       pmax, psum, bb);
    hipLaunchKernelGGL(k2b_stats,  dim3(NB * NC), dim3(256), 0, stream,
                       x, mask, bb, xmax, pooled);
    hipLaunchKernelGGL(k3_gates,   dim3(1024),    dim3(256), 0, stream,
                       pooled, W1, W3, xmax, thres);
    hipLaunchKernelGGL(k4_out,     dim3(NB * NC), dim3(256), 0, stream,
                       x, mask, bb, thres, out);
}